// Round 18
// baseline (182.757 us; speedup 1.0000x reference)
//
#include <hip/hip_runtime.h>

typedef float f32x4 __attribute__((ext_vector_type(4)));

#define AX_X 0
#define AX_W1 1
#define AX_W2 2

// ---------- exact e4m3fn RNE encode (matches ml_dtypes astype) ----------
__device__ __forceinline__ unsigned char fp8_encode(float t) {
  unsigned tb = __float_as_uint(t);
  unsigned sgn = (tb >> 24) & 0x80u;
  float a = fabsf(t);
  unsigned sb = (unsigned)(int)rintf(a * 512.0f);  // subnormal path (|t| < 2^-6)
  unsigned u = tb & 0x7fffffffu;
  unsigned rem = u & 0xFFFFFu;
  unsigned keep = u & ~0xFFFFFu;
  unsigned inc = (rem > 0x80000u || (rem == 0x80000u && (keep & 0x100000u))) ? 0x100000u : 0u;
  keep += inc;
  int e = (int)(keep >> 23) - 127;
  unsigned nb = (unsigned)((e + 7) << 3) | ((keep >> 20) & 7u);
  unsigned b = (a < 0.015625f) ? sb : nb;
  return (unsigned char)(b | sgn);
}

// reduce 64 per-block partial maxima (fmax associative -> bit-identical to global amax)
__device__ __forceinline__ float scale_from(const float* __restrict__ part, int which) {
  float m = 0.f;
#pragma unroll
  for (int i = 0; i < 64; i++) m = fmaxf(m, part[which * 64 + i]);
  return fmaxf(m / 448.0f, 1e-12f);
}

__device__ __forceinline__ float scale_raw(float rawmax) {
  return fmaxf(rawmax / 448.0f, 1e-12f);
}

__device__ __forceinline__ void gll16(const void* g, void* l) {
  __builtin_amdgcn_global_load_lds(
      (const __attribute__((address_space(1))) unsigned int*)g,
      (__attribute__((address_space(3))) unsigned int*)l, 16, 0, 0);
}

// ---------- amax: per-block partial maxima ----------
__global__ __launch_bounds__(256, 4) void k_amax3(const float* __restrict__ x,
                                                  const float* __restrict__ w1,
                                                  const float* __restrict__ w2,
                                                  float* __restrict__ part) {
  __shared__ float wmax[4];
  int which = blockIdx.y;
  const float* p = which == 0 ? x : (which == 1 ? w1 : w2);
  int n4 = which == 0 ? (1048576 / 4) : (2097152 / 4);
  float m = 0.f;
  for (int i = blockIdx.x * 256 + threadIdx.x; i < n4; i += gridDim.x * 256) {
    float4 v = ((const float4*)p)[i];
    m = fmaxf(m, fmaxf(fmaxf(fabsf(v.x), fabsf(v.y)), fmaxf(fabsf(v.z), fabsf(v.w))));
  }
  for (int off = 32; off; off >>= 1) m = fmaxf(m, __shfl_xor(m, off));
  int t = threadIdx.x;
  if ((t & 63) == 0) wmax[t >> 6] = m;
  __syncthreads();
  if (t == 0)
    part[which * 64 + blockIdx.x] =
        fmaxf(fmaxf(wmax[0], wmax[1]), fmaxf(wmax[2], wmax[3]));
}

// ---------- fused quantize: x (blocks 0..255), w1t (256..767), w2-de (768..1279) ----------
__global__ __launch_bounds__(256, 2) void k_quant_all(const float* __restrict__ x,
                                                      const float* __restrict__ w1,
                                                      const float* __restrict__ w2,
                                                      unsigned char* __restrict__ qx,
                                                      unsigned char* __restrict__ qw1t,
                                                      unsigned char* __restrict__ qw2,
                                                      const float* __restrict__ part) {
  __shared__ float tile[64 * 68];  // 17408 B; reused as [32*132] by the w2 branch
  int b = blockIdx.x, t = threadIdx.x;
  if (b < 256) {
    float s = scale_from(part, AX_X);
    int i = b * 256 + t;
    const float4* src = (const float4*)x + (size_t)i * 4;
    union { unsigned char bb[16]; uint4 u; } o;
#pragma unroll
    for (int p = 0; p < 4; p++) {
      float4 v = src[p];
      o.bb[p * 4 + 0] = fp8_encode(v.x / s);
      o.bb[p * 4 + 1] = fp8_encode(v.y / s);
      o.bb[p * 4 + 2] = fp8_encode(v.z / s);
      o.bb[p * 4 + 3] = fp8_encode(v.w / s);
    }
    *(uint4*)(qx + (size_t)i * 16) = o.u;
  } else if (b < 768) {
    float s = scale_from(part, AX_W1);
    int idx = b - 256;
    int n0 = (idx & 63) * 64, c0 = (idx >> 6) * 64;
    int row = t >> 2, q4 = t & 3;
    const float* src = w1 + (size_t)(c0 + row) * 4096 + n0 + q4 * 16;
#pragma unroll
    for (int p = 0; p < 4; p++) {
      float4 v = *(const float4*)(src + p * 4);
      *(float4*)&tile[row * 68 + q4 * 16 + p * 4] = v;
    }
    __syncthreads();
    int nl = t >> 2, ch = t & 3;
    union { unsigned char bb[16]; uint4 u; } o;
#pragma unroll
    for (int j = 0; j < 16; j++) o.bb[j] = fp8_encode(tile[(ch * 16 + j) * 68 + nl] / s);
    *(uint4*)(qw1t + (size_t)(n0 + nl) * 512 + c0 + ch * 16) = o.u;
  } else {
    float s = scale_from(part, AX_W2);
    int row = b - 768;
    const float* sp = w2 + (size_t)row * 4096;
#pragma unroll
    for (int p = 0; p < 4; p++) {
      int n = (p * 256 + t) * 4;
      float4 v = *(const float4*)(sp + n);
      *(float4*)&tile[(n >> 7) * 132 + (n & 127)] = v;
    }
    __syncthreads();
    int e = t >> 1, half = t & 1;
    union { unsigned char bb[16]; uint4 u; } o;
#pragma unroll
    for (int j = 0; j < 16; j++) o.bb[j] = fp8_encode(tile[(half * 16 + j) * 132 + e] / s);
    *(uint4*)(qw2 + ((size_t)e * 512 + row) * 32 + half * 16) = o.u;
  }
}

// ---------- quantize+transpose h: [2048 rows][32d*128e] fp32 -> [128e][2048][32d] fp8 ----------
__global__ __launch_bounds__(256, 2) void k_quant_h(const float* __restrict__ src,
                                                    unsigned char* __restrict__ dst,
                                                    const float* __restrict__ hpart) {
  __shared__ float tile[32 * 132];
  int row = blockIdx.x, t = threadIdx.x;
  // reduce 512 h-partials: 2/thread -> wave shuffle -> LDS -> broadcast
  float2 hv = ((const float2*)hpart)[t];
  float m = fmaxf(hv.x, hv.y);
  for (int off = 32; off; off >>= 1) m = fmaxf(m, __shfl_xor(m, off));
  if ((t & 63) == 0) tile[t >> 6] = m;
  __syncthreads();
  float s = scale_raw(fmaxf(fmaxf(tile[0], tile[1]), fmaxf(tile[2], tile[3])));
  __syncthreads();
  const float* sp = src + (size_t)row * 4096;
#pragma unroll
  for (int p = 0; p < 4; p++) {
    int n = (p * 256 + t) * 4;
    float4 v = *(const float4*)(sp + n);
    *(float4*)&tile[(n >> 7) * 132 + (n & 127)] = v;
  }
  __syncthreads();
  int e = t >> 1, half = t & 1;
  union { unsigned char b[16]; uint4 u; } o;
#pragma unroll
  for (int j = 0; j < 16; j++) o.b[j] = fp8_encode(tile[(half * 16 + j) * 132 + e] / s);
  *(uint4*)(dst + ((size_t)e * 2048 + row) * 32 + half * 16) = o.u;
}

// ---------- GEMM1: h[2048][4096] = (qx @ qw1t^T) * sx*sw1 ----------
// R12 structure (BK=128, 4 planes, LDS-staged). Idempotent: rewrites same h/hpart.
__global__ __launch_bounds__(256, 2) void k_gemm1(const unsigned char* __restrict__ qa,
                                                  const unsigned char* __restrict__ qb,
                                                  float* __restrict__ h,
                                                  const float* __restrict__ part,
                                                  float* __restrict__ hpart) {
  __shared__ unsigned char As[16384], Bs[16384];  // 4 planes x [128 rows][32 k-bytes]
  __shared__ float wred[4];
  int m0 = blockIdx.y * 128, n0 = blockIdx.x * 128;
  int t = threadIdx.x, lane = t & 63, w = t >> 6, wr = w >> 1, wc = w & 1;
  f32x4 acc[4][4] = {};
  const unsigned char* ag = qa + (size_t)(m0 + (t >> 1)) * 512 + (t & 1) * 16;
  const unsigned char* bg = qb + (size_t)(n0 + (t >> 1)) * 512 + (t & 1) * 16;
  const int ldst = 16 * t;
  const int abase = (wr * 64 + (lane & 15)) * 32 + ((lane >> 4) << 3);
  const int bbase = (wc * 64 + (lane & 15)) * 32 + ((lane >> 4) << 3);

  for (int k0 = 0; k0 < 512; k0 += 128) {
#pragma unroll
    for (int j = 0; j < 4; j++) {
      gll16(ag + k0 + j * 32, As + j * 4096 + ldst);
      gll16(bg + k0 + j * 32, Bs + j * 4096 + ldst);
    }
    __syncthreads();
#pragma unroll
    for (int kk = 0; kk < 4; kk++) {
      long a[4], b[4];
#pragma unroll
      for (int i = 0; i < 4; i++) {
        a[i] = *(const long*)(As + kk * 4096 + abase + i * 512);
        b[i] = *(const long*)(Bs + kk * 4096 + bbase + i * 512);
      }
#pragma unroll
      for (int mi = 0; mi < 4; mi++)
#pragma unroll
        for (int ni = 0; ni < 4; ni++)
          acc[mi][ni] = __builtin_amdgcn_mfma_f32_16x16x32_fp8_fp8(a[mi], b[ni], acc[mi][ni], 0, 0, 0);
    }
    __syncthreads();
  }

  float s1 = scale_from(part, AX_X) * scale_from(part, AX_W1);
  float lmax = 0.f;
#pragma unroll
  for (int mi = 0; mi < 4; mi++)
#pragma unroll
    for (int ni = 0; ni < 4; ni++)
#pragma unroll
      for (int r = 0; r < 4; r++) {
        float v = acc[mi][ni][r] * s1;
        h[(size_t)(m0 + wr * 64 + mi * 16 + ((lane >> 4) << 2) + r) * 4096 +
          (n0 + wc * 64 + ni * 16 + (lane & 15))] = v;
        lmax = fmaxf(lmax, fabsf(v));
      }
  for (int off = 32; off; off >>= 1) lmax = fmaxf(lmax, __shfl_xor(lmax, off));
  if (lane == 0) wred[w] = lmax;
  __syncthreads();
  if (t == 0)
    hpart[blockIdx.y * 32 + blockIdx.x] =
        fmaxf(fmaxf(wred[0], wred[1]), fmaxf(wred[2], wred[3]));
}

// ---------- GEMM2: out[m][c][e] = s2 * sum_d qh[e][m][d]*qw2[e][c][d] ----------
// 32m x 16c block, 512 thr / 8 waves; pad 34; full-128B-line NT stores.
__global__ __launch_bounds__(512, 2) void k_gemm2(const unsigned char* __restrict__ qh,
                                                  const unsigned char* __restrict__ qw2,
                                                  const float* __restrict__ part,
                                                  const float* __restrict__ hpart,
                                                  float* __restrict__ out) {
  __shared__ float lbuf[8 * 64 * 34];  // 69632 B
  int bid = blockIdx.x;
  int sw = (bid & 7) * 256 + (bid >> 3);          // bijective, 2048 % 8 == 0
  int m0 = (sw >> 5) * 32, c0 = (sw & 31) * 16;
  int t = threadIdx.x, lane = t & 63, w = t >> 6;  // w in 0..7
  // reduce 512 h-partials: 1/thread -> wave shuffle -> LDS -> broadcast
  float m = hpart[t];
  for (int off = 32; off; off >>= 1) m = fmaxf(m, __shfl_xor(m, off));
  if (lane == 0) lbuf[w] = m;
  __syncthreads();
  float hm = lbuf[0];
#pragma unroll
  for (int i = 1; i < 8; i++) hm = fmaxf(hm, lbuf[i]);
  float s2 = scale_raw(hm) * scale_from(part, AX_W2);
  __syncthreads();

  int mw = m0 + (w >> 2) * 16;
  int e0 = (w & 3) * 32;
  const unsigned char* A = qh + ((size_t)e0 * 2048 + mw + (lane & 15)) * 32 + ((lane >> 4) << 3);
  const unsigned char* B = qw2 + ((size_t)e0 * 512 + c0 + (lane & 15)) * 32 + ((lane >> 4) << 3);
  f32x4 acc[32];
#pragma unroll
  for (int e = 0; e < 32; e++) {
    long a = *(const long*)(A + (size_t)e * 2048 * 32);
    long b = *(const long*)(B + (size_t)e * 512 * 32);
    f32x4 z = {0.f, 0.f, 0.f, 0.f};
    acc[e] = __builtin_amdgcn_mfma_f32_16x16x32_fp8_fp8(a, b, z, 0, 0, 0);
  }
  float* lw = lbuf + w * (64 * 34);
#pragma unroll
  for (int r = 0; r < 4; r++) {
#pragma unroll
    for (int g = 0; g < 8; g++) {
      *(float2*)&lw[lane * 34 + 4 * g] =
          make_float2(acc[4 * g + 0][r] * s2, acc[4 * g + 1][r] * s2);
      *(float2*)&lw[lane * 34 + 4 * g + 2] =
          make_float2(acc[4 * g + 2][r] * s2, acc[4 * g + 3][r] * s2);
    }
#pragma unroll
    for (int i = 0; i < 8; i++) {
      int p = i * 8 + (lane >> 3);
      float2 u0 = *(const float2*)&lw[p * 34 + (lane & 7) * 4];
      float2 u1 = *(const float2*)&lw[p * 34 + (lane & 7) * 4 + 2];
      float* dst = out + ((size_t)(mw + ((p >> 4) << 2) + r) * 512 + c0 + (p & 15)) * 128 +
                   e0 + (lane & 7) * 4;
      f32x4 vv = {u0.x, u0.y, u1.x, u1.y};
      __builtin_nontemporal_store(vv, (f32x4*)dst);
    }
  }
}

extern "C" void kernel_launch(void* const* d_in, const int* in_sizes, int n_in,
                              void* d_out, int out_size, void* d_ws, size_t ws_size,
                              hipStream_t stream) {
  const float* x  = (const float*)d_in[0];   // [2048][512]
  const float* w1 = (const float*)d_in[1];   // [512][4096]
  const float* w2 = (const float*)d_in[2];   // [512][4096]
  float* out = (float*)d_out;                // [2048][512][128]

  float* part  = (float*)d_ws;                         // 192 partial maxima (x,w1,w2)
  float* hpart = (float*)d_ws + 256;                   // 512 h partial maxima
  unsigned char* base = (unsigned char*)d_ws + 4096;
  unsigned char* qx   = base;                          // 1 MB  [2048][512]
  unsigned char* qw1t = qx   + (size_t)2048 * 512;     // 2 MB  [4096][512]
  unsigned char* qw2  = qw1t + (size_t)4096 * 512;     // 2 MB  [128][512][32]
  unsigned char* qh   = qw2  + (size_t)128 * 512 * 32; // 8 MB  [128][2048][32]
  float* h = (float*)(qh + (size_t)128 * 2048 * 32);   // 32 MB [2048][4096]

  k_amax3<<<dim3(64, 3), dim3(256), 0, stream>>>(x, w1, w2, part);
  k_quant_all<<<dim3(1280), dim3(256), 0, stream>>>(x, w1, w2, qx, qw1t, qw2, part);
  // MEASUREMENT: gemm1 doubled (idempotent; identical h/hpart bytes).
  // dur - 164.9 = t_gemm1 + o. Revert to single launch next round.
  k_gemm1<<<dim3(32, 16), dim3(256), 0, stream>>>(qx, qw1t, h, part, hpart);
  k_gemm1<<<dim3(32, 16), dim3(256), 0, stream>>>(qx, qw1t, h, part, hpart);
  k_quant_h<<<dim3(2048), dim3(256), 0, stream>>>(h, qh, hpart);
  k_gemm2<<<dim3(2048), dim3(512), 0, stream>>>(qh, qw2, part, hpart, out);
}

// Round 19
// 164.526 us; speedup vs baseline: 1.1108x; 1.1108x over previous
//
#include <hip/hip_runtime.h>

typedef float f32x4 __attribute__((ext_vector_type(4)));

#define AX_X 0
#define AX_W1 1
#define AX_W2 2

// ---------- exact e4m3fn RNE encode (matches ml_dtypes astype) ----------
__device__ __forceinline__ unsigned char fp8_encode(float t) {
  unsigned tb = __float_as_uint(t);
  unsigned sgn = (tb >> 24) & 0x80u;
  float a = fabsf(t);
  unsigned sb = (unsigned)(int)rintf(a * 512.0f);  // subnormal path (|t| < 2^-6)
  unsigned u = tb & 0x7fffffffu;
  unsigned rem = u & 0xFFFFFu;
  unsigned keep = u & ~0xFFFFFu;
  unsigned inc = (rem > 0x80000u || (rem == 0x80000u && (keep & 0x100000u))) ? 0x100000u : 0u;
  keep += inc;
  int e = (int)(keep >> 23) - 127;
  unsigned nb = (unsigned)((e + 7) << 3) | ((keep >> 20) & 7u);
  unsigned b = (a < 0.015625f) ? sb : nb;
  return (unsigned char)(b | sgn);
}

// reduce 64 per-block partial maxima (fmax associative -> bit-identical to global amax)
__device__ __forceinline__ float scale_from(const float* __restrict__ part, int which) {
  float m = 0.f;
#pragma unroll
  for (int i = 0; i < 64; i++) m = fmaxf(m, part[which * 64 + i]);
  return fmaxf(m / 448.0f, 1e-12f);
}

__device__ __forceinline__ float scale_raw(float rawmax) {
  return fmaxf(rawmax / 448.0f, 1e-12f);
}

__device__ __forceinline__ void gll16(const void* g, void* l) {
  __builtin_amdgcn_global_load_lds(
      (const __attribute__((address_space(1))) unsigned int*)g,
      (__attribute__((address_space(3))) unsigned int*)l, 16, 0, 0);
}

// ---------- amax: per-block partial maxima ----------
__global__ __launch_bounds__(256, 4) void k_amax3(const float* __restrict__ x,
                                                  const float* __restrict__ w1,
                                                  const float* __restrict__ w2,
                                                  float* __restrict__ part) {
  __shared__ float wmax[4];
  int which = blockIdx.y;
  const float* p = which == 0 ? x : (which == 1 ? w1 : w2);
  int n4 = which == 0 ? (1048576 / 4) : (2097152 / 4);
  float m = 0.f;
  for (int i = blockIdx.x * 256 + threadIdx.x; i < n4; i += gridDim.x * 256) {
    float4 v = ((const float4*)p)[i];
    m = fmaxf(m, fmaxf(fmaxf(fabsf(v.x), fabsf(v.y)), fmaxf(fabsf(v.z), fabsf(v.w))));
  }
  for (int off = 32; off; off >>= 1) m = fmaxf(m, __shfl_xor(m, off));
  int t = threadIdx.x;
  if ((t & 63) == 0) wmax[t >> 6] = m;
  __syncthreads();
  if (t == 0)
    part[which * 64 + blockIdx.x] =
        fmaxf(fmaxf(wmax[0], wmax[1]), fmaxf(wmax[2], wmax[3]));
}

// ---------- fused quantize: x (blocks 0..255), w1t (256..767), w2-de (768..1279) ----------
// (256,4): 2x resident waves for this memory-bound kernel.
// w2 branch: XCD-aligned row swizzle -- consecutive rows (sharing 128B qw2
// lines) are processed by same-XCD blocks, so lines complete in one L2
// (no cross-XCD partial-line RMW to HBM).
__global__ __launch_bounds__(256, 4) void k_quant_all(const float* __restrict__ x,
                                                      const float* __restrict__ w1,
                                                      const float* __restrict__ w2,
                                                      unsigned char* __restrict__ qx,
                                                      unsigned char* __restrict__ qw1t,
                                                      unsigned char* __restrict__ qw2,
                                                      const float* __restrict__ part) {
  __shared__ float tile[64 * 68];  // 17408 B; reused as [32*132] by the w2 branch
  int b = blockIdx.x, t = threadIdx.x;
  if (b < 256) {
    float s = scale_from(part, AX_X);
    int i = b * 256 + t;
    const float4* src = (const float4*)x + (size_t)i * 4;
    union { unsigned char bb[16]; uint4 u; } o;
#pragma unroll
    for (int p = 0; p < 4; p++) {
      float4 v = src[p];
      o.bb[p * 4 + 0] = fp8_encode(v.x / s);
      o.bb[p * 4 + 1] = fp8_encode(v.y / s);
      o.bb[p * 4 + 2] = fp8_encode(v.z / s);
      o.bb[p * 4 + 3] = fp8_encode(v.w / s);
    }
    *(uint4*)(qx + (size_t)i * 16) = o.u;
  } else if (b < 768) {
    float s = scale_from(part, AX_W1);
    int idx = b - 256;
    int n0 = (idx & 63) * 64, c0 = (idx >> 6) * 64;
    int row = t >> 2, q4 = t & 3;
    const float* src = w1 + (size_t)(c0 + row) * 4096 + n0 + q4 * 16;
#pragma unroll
    for (int p = 0; p < 4; p++) {
      float4 v = *(const float4*)(src + p * 4);
      *(float4*)&tile[row * 68 + q4 * 16 + p * 4] = v;
    }
    __syncthreads();
    int nl = t >> 2, ch = t & 3;
    union { unsigned char bb[16]; uint4 u; } o;
#pragma unroll
    for (int j = 0; j < 16; j++) o.bb[j] = fp8_encode(tile[(ch * 16 + j) * 68 + nl] / s);
    *(uint4*)(qw1t + (size_t)(n0 + nl) * 512 + c0 + ch * 16) = o.u;
  } else {
    float s = scale_from(part, AX_W2);
    int i = b - 768;
    int row = (i & 7) * 64 + (i >> 3);  // XCD-aligned: XCD k owns rows 64k..64k+63
    const float* sp = w2 + (size_t)row * 4096;
#pragma unroll
    for (int p = 0; p < 4; p++) {
      int n = (p * 256 + t) * 4;
      float4 v = *(const float4*)(sp + n);
      *(float4*)&tile[(n >> 7) * 132 + (n & 127)] = v;
    }
    __syncthreads();
    int e = t >> 1, half = t & 1;
    union { unsigned char bb[16]; uint4 u; } o;
#pragma unroll
    for (int j = 0; j < 16; j++) o.bb[j] = fp8_encode(tile[(half * 16 + j) * 132 + e] / s);
    *(uint4*)(qw2 + ((size_t)e * 512 + row) * 32 + half * 16) = o.u;
  }
}

// ---------- quantize+transpose h: [2048 rows][32d*128e] fp32 -> [128e][2048][32d] fp8 ----------
// (256,4) occupancy; XCD-aligned row swizzle (qh 128B lines span 4 rows ->
// keep row-quads on one XCD's L2 so lines complete before writeback).
__global__ __launch_bounds__(256, 4) void k_quant_h(const float* __restrict__ src,
                                                    unsigned char* __restrict__ dst,
                                                    const float* __restrict__ hpart) {
  __shared__ float tile[32 * 132];
  int bid = blockIdx.x;
  int row = (bid & 7) * 256 + (bid >> 3);  // XCD k owns rows 256k..256k+255
  int t = threadIdx.x;
  // reduce 512 h-partials: 2/thread -> wave shuffle -> LDS -> broadcast
  float2 hv = ((const float2*)hpart)[t];
  float m = fmaxf(hv.x, hv.y);
  for (int off = 32; off; off >>= 1) m = fmaxf(m, __shfl_xor(m, off));
  if ((t & 63) == 0) tile[t >> 6] = m;
  __syncthreads();
  float s = scale_raw(fmaxf(fmaxf(tile[0], tile[1]), fmaxf(tile[2], tile[3])));
  __syncthreads();
  const float* sp = src + (size_t)row * 4096;
#pragma unroll
  for (int p = 0; p < 4; p++) {
    int n = (p * 256 + t) * 4;
    float4 v = *(const float4*)(sp + n);
    *(float4*)&tile[(n >> 7) * 132 + (n & 127)] = v;
  }
  __syncthreads();
  int e = t >> 1, half = t & 1;
  union { unsigned char b[16]; uint4 u; } o;
#pragma unroll
  for (int j = 0; j < 16; j++) o.b[j] = fp8_encode(tile[(half * 16 + j) * 132 + e] / s);
  *(uint4*)(dst + ((size_t)e * 2048 + row) * 32 + half * 16) = o.u;
}

// ---------- GEMM1: h[2048][4096] = (qx @ qw1t^T) * sx*sw1 ----------
// R12 structure (BK=128, 4 planes, LDS-staged); measured t ~= 15us.
__global__ __launch_bounds__(256, 2) void k_gemm1(const unsigned char* __restrict__ qa,
                                                  const unsigned char* __restrict__ qb,
                                                  float* __restrict__ h,
                                                  const float* __restrict__ part,
                                                  float* __restrict__ hpart) {
  __shared__ unsigned char As[16384], Bs[16384];  // 4 planes x [128 rows][32 k-bytes]
  __shared__ float wred[4];
  int m0 = blockIdx.y * 128, n0 = blockIdx.x * 128;
  int t = threadIdx.x, lane = t & 63, w = t >> 6, wr = w >> 1, wc = w & 1;
  f32x4 acc[4][4] = {};
  const unsigned char* ag = qa + (size_t)(m0 + (t >> 1)) * 512 + (t & 1) * 16;
  const unsigned char* bg = qb + (size_t)(n0 + (t >> 1)) * 512 + (t & 1) * 16;
  const int ldst = 16 * t;
  const int abase = (wr * 64 + (lane & 15)) * 32 + ((lane >> 4) << 3);
  const int bbase = (wc * 64 + (lane & 15)) * 32 + ((lane >> 4) << 3);

  for (int k0 = 0; k0 < 512; k0 += 128) {
#pragma unroll
    for (int j = 0; j < 4; j++) {
      gll16(ag + k0 + j * 32, As + j * 4096 + ldst);
      gll16(bg + k0 + j * 32, Bs + j * 4096 + ldst);
    }
    __syncthreads();
#pragma unroll
    for (int kk = 0; kk < 4; kk++) {
      long a[4], b[4];
#pragma unroll
      for (int i = 0; i < 4; i++) {
        a[i] = *(const long*)(As + kk * 4096 + abase + i * 512);
        b[i] = *(const long*)(Bs + kk * 4096 + bbase + i * 512);
      }
#pragma unroll
      for (int mi = 0; mi < 4; mi++)
#pragma unroll
        for (int ni = 0; ni < 4; ni++)
          acc[mi][ni] = __builtin_amdgcn_mfma_f32_16x16x32_fp8_fp8(a[mi], b[ni], acc[mi][ni], 0, 0, 0);
    }
    __syncthreads();
  }

  float s1 = scale_from(part, AX_X) * scale_from(part, AX_W1);
  float lmax = 0.f;
#pragma unroll
  for (int mi = 0; mi < 4; mi++)
#pragma unroll
    for (int ni = 0; ni < 4; ni++)
#pragma unroll
      for (int r = 0; r < 4; r++) {
        float v = acc[mi][ni][r] * s1;
        h[(size_t)(m0 + wr * 64 + mi * 16 + ((lane >> 4) << 2) + r) * 4096 +
          (n0 + wc * 64 + ni * 16 + (lane & 15))] = v;
        lmax = fmaxf(lmax, fabsf(v));
      }
  for (int off = 32; off; off >>= 1) lmax = fmaxf(lmax, __shfl_xor(lmax, off));
  if (lane == 0) wred[w] = lmax;
  __syncthreads();
  if (t == 0)
    hpart[blockIdx.y * 32 + blockIdx.x] =
        fmaxf(fmaxf(wred[0], wred[1]), fmaxf(wred[2], wred[3]));
}

// ---------- GEMM2: out[m][c][e] = s2 * sum_d qh[e][m][d]*qw2[e][c][d] ----------
// 32m x 16c block, 512 thr / 8 waves; pad 34; full-128B-line NT stores.
__global__ __launch_bounds__(512, 2) void k_gemm2(const unsigned char* __restrict__ qh,
                                                  const unsigned char* __restrict__ qw2,
                                                  const float* __restrict__ part,
                                                  const float* __restrict__ hpart,
                                                  float* __restrict__ out) {
  __shared__ float lbuf[8 * 64 * 34];  // 69632 B
  int bid = blockIdx.x;
  int sw = (bid & 7) * 256 + (bid >> 3);          // bijective, 2048 % 8 == 0
  int m0 = (sw >> 5) * 32, c0 = (sw & 31) * 16;
  int t = threadIdx.x, lane = t & 63, w = t >> 6;  // w in 0..7
  // reduce 512 h-partials: 1/thread -> wave shuffle -> LDS -> broadcast
  float m = hpart[t];
  for (int off = 32; off; off >>= 1) m = fmaxf(m, __shfl_xor(m, off));
  if (lane == 0) lbuf[w] = m;
  __syncthreads();
  float hm = lbuf[0];
#pragma unroll
  for (int i = 1; i < 8; i++) hm = fmaxf(hm, lbuf[i]);
  float s2 = scale_raw(hm) * scale_from(part, AX_W2);
  __syncthreads();

  int mw = m0 + (w >> 2) * 16;
  int e0 = (w & 3) * 32;
  const unsigned char* A = qh + ((size_t)e0 * 2048 + mw + (lane & 15)) * 32 + ((lane >> 4) << 3);
  const unsigned char* B = qw2 + ((size_t)e0 * 512 + c0 + (lane & 15)) * 32 + ((lane >> 4) << 3);
  f32x4 acc[32];
#pragma unroll
  for (int e = 0; e < 32; e++) {
    long a = *(const long*)(A + (size_t)e * 2048 * 32);
    long b = *(const long*)(B + (size_t)e * 512 * 32);
    f32x4 z = {0.f, 0.f, 0.f, 0.f};
    acc[e] = __builtin_amdgcn_mfma_f32_16x16x32_fp8_fp8(a, b, z, 0, 0, 0);
  }
  float* lw = lbuf + w * (64 * 34);
#pragma unroll
  for (int r = 0; r < 4; r++) {
#pragma unroll
    for (int g = 0; g < 8; g++) {
      *(float2*)&lw[lane * 34 + 4 * g] =
          make_float2(acc[4 * g + 0][r] * s2, acc[4 * g + 1][r] * s2);
      *(float2*)&lw[lane * 34 + 4 * g + 2] =
          make_float2(acc[4 * g + 2][r] * s2, acc[4 * g + 3][r] * s2);
    }
#pragma unroll
    for (int i = 0; i < 8; i++) {
      int p = i * 8 + (lane >> 3);
      float2 u0 = *(const float2*)&lw[p * 34 + (lane & 7) * 4];
      float2 u1 = *(const float2*)&lw[p * 34 + (lane & 7) * 4 + 2];
      float* dst = out + ((size_t)(mw + ((p >> 4) << 2) + r) * 512 + c0 + (p & 15)) * 128 +
                   e0 + (lane & 7) * 4;
      f32x4 vv = {u0.x, u0.y, u1.x, u1.y};
      __builtin_nontemporal_store(vv, (f32x4*)dst);
    }
  }
}

extern "C" void kernel_launch(void* const* d_in, const int* in_sizes, int n_in,
                              void* d_out, int out_size, void* d_ws, size_t ws_size,
                              hipStream_t stream) {
  const float* x  = (const float*)d_in[0];   // [2048][512]
  const float* w1 = (const float*)d_in[1];   // [512][4096]
  const float* w2 = (const float*)d_in[2];   // [512][4096]
  float* out = (float*)d_out;                // [2048][512][128]

  float* part  = (float*)d_ws;                         // 192 partial maxima (x,w1,w2)
  float* hpart = (float*)d_ws + 256;                   // 512 h partial maxima
  unsigned char* base = (unsigned char*)d_ws + 4096;
  unsigned char* qx   = base;                          // 1 MB  [2048][512]
  unsigned char* qw1t = qx   + (size_t)2048 * 512;     // 2 MB  [4096][512]
  unsigned char* qw2  = qw1t + (size_t)4096 * 512;     // 2 MB  [128][512][32]
  unsigned char* qh   = qw2  + (size_t)128 * 512 * 32; // 8 MB  [128][2048][32]
  float* h = (float*)(qh + (size_t)128 * 2048 * 32);   // 32 MB [2048][4096]

  k_amax3<<<dim3(64, 3), dim3(256), 0, stream>>>(x, w1, w2, part);
  k_quant_all<<<dim3(1280), dim3(256), 0, stream>>>(x, w1, w2, qx, qw1t, qw2, part);
  k_gemm1<<<dim3(32, 16), dim3(256), 0, stream>>>(qx, qw1t, h, part, hpart);
  k_quant_h<<<dim3(2048), dim3(256), 0, stream>>>(h, qh, hpart);
  k_gemm2<<<dim3(2048), dim3(512), 0, stream>>>(qh, qw2, part, hpart, out);
}

// Round 20
// 152.216 us; speedup vs baseline: 1.2006x; 1.0809x over previous
//
#include <hip/hip_runtime.h>

typedef float f32x4 __attribute__((ext_vector_type(4)));

#define AX_X 0
#define AX_W1 1
#define AX_W2 2

// ---------- exact e4m3fn RNE encode (matches ml_dtypes astype) ----------
__device__ __forceinline__ unsigned char fp8_encode(float t) {
  unsigned tb = __float_as_uint(t);
  unsigned sgn = (tb >> 24) & 0x80u;
  float a = fabsf(t);
  unsigned sb = (unsigned)(int)rintf(a * 512.0f);  // subnormal path (|t| < 2^-6)
  unsigned u = tb & 0x7fffffffu;
  unsigned rem = u & 0xFFFFFu;
  unsigned keep = u & ~0xFFFFFu;
  unsigned inc = (rem > 0x80000u || (rem == 0x80000u && (keep & 0x100000u))) ? 0x100000u : 0u;
  keep += inc;
  int e = (int)(keep >> 23) - 127;
  unsigned nb = (unsigned)((e + 7) << 3) | ((keep >> 20) & 7u);
  unsigned b = (a < 0.015625f) ? sb : nb;
  return (unsigned char)(b | sgn);
}

// reduce 64 per-block partial maxima (fmax associative -> bit-identical to global amax)
__device__ __forceinline__ float scale_from(const float* __restrict__ part, int which) {
  float m = 0.f;
#pragma unroll
  for (int i = 0; i < 64; i++) m = fmaxf(m, part[which * 64 + i]);
  return fmaxf(m / 448.0f, 1e-12f);
}

__device__ __forceinline__ float scale_raw(float rawmax) {
  return fmaxf(rawmax / 448.0f, 1e-12f);
}

__device__ __forceinline__ void gll16(const void* g, void* l) {
  __builtin_amdgcn_global_load_lds(
      (const __attribute__((address_space(1))) unsigned int*)g,
      (__attribute__((address_space(3))) unsigned int*)l, 16, 0, 0);
}

// ---------- amax: per-block partial maxima ----------
__global__ __launch_bounds__(256, 4) void k_amax3(const float* __restrict__ x,
                                                  const float* __restrict__ w1,
                                                  const float* __restrict__ w2,
                                                  float* __restrict__ part) {
  __shared__ float wmax[4];
  int which = blockIdx.y;
  const float* p = which == 0 ? x : (which == 1 ? w1 : w2);
  int n4 = which == 0 ? (1048576 / 4) : (2097152 / 4);
  float m = 0.f;
  for (int i = blockIdx.x * 256 + threadIdx.x; i < n4; i += gridDim.x * 256) {
    float4 v = ((const float4*)p)[i];
    m = fmaxf(m, fmaxf(fmaxf(fabsf(v.x), fabsf(v.y)), fmaxf(fabsf(v.z), fabsf(v.w))));
  }
  for (int off = 32; off; off >>= 1) m = fmaxf(m, __shfl_xor(m, off));
  int t = threadIdx.x;
  if ((t & 63) == 0) wmax[t >> 6] = m;
  __syncthreads();
  if (t == 0)
    part[which * 64 + blockIdx.x] =
        fmaxf(fmaxf(wmax[0], wmax[1]), fmaxf(wmax[2], wmax[3]));
}

// ---------- fused quantize: x (blocks 0..255), w1t (256..767), w2-de (768..1279) ----------
// Block 0 also precomputes s1 = sx*sw1 (for gemm1) and sw2 (for quant_h/gemm2)
// with the identical fmax chains -> bit-identical scales, stream-ordered.
__global__ __launch_bounds__(256, 4) void k_quant_all(const float* __restrict__ x,
                                                      const float* __restrict__ w1,
                                                      const float* __restrict__ w2,
                                                      unsigned char* __restrict__ qx,
                                                      unsigned char* __restrict__ qw1t,
                                                      unsigned char* __restrict__ qw2,
                                                      const float* __restrict__ part,
                                                      float* __restrict__ sc) {
  __shared__ float tile[64 * 68];  // 17408 B; reused as [32*132] by the w2 branch
  int b = blockIdx.x, t = threadIdx.x;
  if (b == 0 && t == 0) {
    sc[0] = scale_from(part, AX_X) * scale_from(part, AX_W1);  // s1
    sc[1] = scale_from(part, AX_W2);                           // sw2
  }
  if (b < 256) {
    float s = scale_from(part, AX_X);
    int i = b * 256 + t;
    const float4* src = (const float4*)x + (size_t)i * 4;
    union { unsigned char bb[16]; uint4 u; } o;
#pragma unroll
    for (int p = 0; p < 4; p++) {
      float4 v = src[p];
      o.bb[p * 4 + 0] = fp8_encode(v.x / s);
      o.bb[p * 4 + 1] = fp8_encode(v.y / s);
      o.bb[p * 4 + 2] = fp8_encode(v.z / s);
      o.bb[p * 4 + 3] = fp8_encode(v.w / s);
    }
    *(uint4*)(qx + (size_t)i * 16) = o.u;
  } else if (b < 768) {
    float s = scale_from(part, AX_W1);
    int idx = b - 256;
    int n0 = (idx & 63) * 64, c0 = (idx >> 6) * 64;
    int row = t >> 2, q4 = t & 3;
    const float* src = w1 + (size_t)(c0 + row) * 4096 + n0 + q4 * 16;
#pragma unroll
    for (int p = 0; p < 4; p++) {
      float4 v = *(const float4*)(src + p * 4);
      *(float4*)&tile[row * 68 + q4 * 16 + p * 4] = v;
    }
    __syncthreads();
    int nl = t >> 2, ch = t & 3;
    union { unsigned char bb[16]; uint4 u; } o;
#pragma unroll
    for (int j = 0; j < 16; j++) o.bb[j] = fp8_encode(tile[(ch * 16 + j) * 68 + nl] / s);
    *(uint4*)(qw1t + (size_t)(n0 + nl) * 512 + c0 + ch * 16) = o.u;
  } else {
    float s = scale_from(part, AX_W2);
    int i = b - 768;
    int row = (i & 7) * 64 + (i >> 3);  // XCD-aligned row order
    const float* sp = w2 + (size_t)row * 4096;
#pragma unroll
    for (int p = 0; p < 4; p++) {
      int n = (p * 256 + t) * 4;
      float4 v = *(const float4*)(sp + n);
      *(float4*)&tile[(n >> 7) * 132 + (n & 127)] = v;
    }
    __syncthreads();
    int e = t >> 1, half = t & 1;
    union { unsigned char bb[16]; uint4 u; } o;
#pragma unroll
    for (int j = 0; j < 16; j++) o.bb[j] = fp8_encode(tile[(half * 16 + j) * 132 + e] / s);
    *(uint4*)(qw2 + ((size_t)e * 512 + row) * 32 + half * 16) = o.u;
  }
}

// ---------- quantize+transpose h: [2048 rows][32d*128e] fp32 -> [128e][2048][32d] fp8 ----------
// Block 0 also stores s2 = scale_raw(hmax)*sw2 (identical ops to the old gemm2
// prologue -> bit-identical), so gemm2 needs only one uniform load.
__global__ __launch_bounds__(256, 4) void k_quant_h(const float* __restrict__ src,
                                                    unsigned char* __restrict__ dst,
                                                    const float* __restrict__ hpart,
                                                    float* __restrict__ sc) {
  __shared__ float tile[32 * 132];
  int bid = blockIdx.x;
  int row = (bid & 7) * 256 + (bid >> 3);  // XCD-aligned row order
  int t = threadIdx.x;
  // reduce 512 h-partials: 2/thread -> wave shuffle -> LDS -> broadcast
  float2 hv = ((const float2*)hpart)[t];
  float m = fmaxf(hv.x, hv.y);
  for (int off = 32; off; off >>= 1) m = fmaxf(m, __shfl_xor(m, off));
  if ((t & 63) == 0) tile[t >> 6] = m;
  __syncthreads();
  float hm = fmaxf(fmaxf(tile[0], tile[1]), fmaxf(tile[2], tile[3]));
  float s = scale_raw(hm);
  if (bid == 0 && t == 0) sc[2] = s * sc[1];  // s2 for gemm2
  __syncthreads();
  const float* sp = src + (size_t)row * 4096;
#pragma unroll
  for (int p = 0; p < 4; p++) {
    int n = (p * 256 + t) * 4;
    float4 v = *(const float4*)(sp + n);
    *(float4*)&tile[(n >> 7) * 132 + (n & 127)] = v;
  }
  __syncthreads();
  int e = t >> 1, half = t & 1;
  union { unsigned char b[16]; uint4 u; } o;
#pragma unroll
  for (int j = 0; j < 16; j++) o.b[j] = fp8_encode(tile[(half * 16 + j) * 132 + e] / s);
  *(uint4*)(dst + ((size_t)e * 2048 + row) * 32 + half * 16) = o.u;
}

// ---------- GEMM1: h[2048][4096] = (qx @ qw1t^T) * s1 ----------
// R12 structure (BK=128, 4 planes, LDS-staged); s1 precomputed (one uniform load).
__global__ __launch_bounds__(256, 2) void k_gemm1(const unsigned char* __restrict__ qa,
                                                  const unsigned char* __restrict__ qb,
                                                  float* __restrict__ h,
                                                  const float* __restrict__ sc,
                                                  float* __restrict__ hpart) {
  __shared__ unsigned char As[16384], Bs[16384];  // 4 planes x [128 rows][32 k-bytes]
  __shared__ float wred[4];
  int m0 = blockIdx.y * 128, n0 = blockIdx.x * 128;
  int t = threadIdx.x, lane = t & 63, w = t >> 6, wr = w >> 1, wc = w & 1;
  f32x4 acc[4][4] = {};
  const unsigned char* ag = qa + (size_t)(m0 + (t >> 1)) * 512 + (t & 1) * 16;
  const unsigned char* bg = qb + (size_t)(n0 + (t >> 1)) * 512 + (t & 1) * 16;
  const int ldst = 16 * t;
  const int abase = (wr * 64 + (lane & 15)) * 32 + ((lane >> 4) << 3);
  const int bbase = (wc * 64 + (lane & 15)) * 32 + ((lane >> 4) << 3);

  for (int k0 = 0; k0 < 512; k0 += 128) {
#pragma unroll
    for (int j = 0; j < 4; j++) {
      gll16(ag + k0 + j * 32, As + j * 4096 + ldst);
      gll16(bg + k0 + j * 32, Bs + j * 4096 + ldst);
    }
    __syncthreads();
#pragma unroll
    for (int kk = 0; kk < 4; kk++) {
      long a[4], b[4];
#pragma unroll
      for (int i = 0; i < 4; i++) {
        a[i] = *(const long*)(As + kk * 4096 + abase + i * 512);
        b[i] = *(const long*)(Bs + kk * 4096 + bbase + i * 512);
      }
#pragma unroll
      for (int mi = 0; mi < 4; mi++)
#pragma unroll
        for (int ni = 0; ni < 4; ni++)
          acc[mi][ni] = __builtin_amdgcn_mfma_f32_16x16x32_fp8_fp8(a[mi], b[ni], acc[mi][ni], 0, 0, 0);
    }
    __syncthreads();
  }

  float s1 = sc[0];
  float lmax = 0.f;
#pragma unroll
  for (int mi = 0; mi < 4; mi++)
#pragma unroll
    for (int ni = 0; ni < 4; ni++)
#pragma unroll
      for (int r = 0; r < 4; r++) {
        float v = acc[mi][ni][r] * s1;
        h[(size_t)(m0 + wr * 64 + mi * 16 + ((lane >> 4) << 2) + r) * 4096 +
          (n0 + wc * 64 + ni * 16 + (lane & 15))] = v;
        lmax = fmaxf(lmax, fabsf(v));
      }
  for (int off = 32; off; off >>= 1) lmax = fmaxf(lmax, __shfl_xor(lmax, off));
  if (lane == 0) wred[w] = lmax;
  __syncthreads();
  if (t == 0)
    hpart[blockIdx.y * 32 + blockIdx.x] =
        fmaxf(fmaxf(wred[0], wred[1]), fmaxf(wred[2], wred[3]));
}

// ---------- GEMM2: out[m][c][e] = s2 * sum_d qh[e][m][d]*qw2[e][c][d] ----------
// 32m x 16c block, 512 thr / 8 waves; pad 34; full-128B-line NT stores.
// s2 precomputed by quant_h -> prologue is a single uniform load (no barriers).
__global__ __launch_bounds__(512, 2) void k_gemm2(const unsigned char* __restrict__ qh,
                                                  const unsigned char* __restrict__ qw2,
                                                  const float* __restrict__ sc,
                                                  float* __restrict__ out) {
  __shared__ float lbuf[8 * 64 * 34];  // 69632 B
  int bid = blockIdx.x;
  int sw = (bid & 7) * 256 + (bid >> 3);          // bijective, 2048 % 8 == 0
  int m0 = (sw >> 5) * 32, c0 = (sw & 31) * 16;
  int t = threadIdx.x, lane = t & 63, w = t >> 6;  // w in 0..7
  float s2 = sc[2];

  int mw = m0 + (w >> 2) * 16;
  int e0 = (w & 3) * 32;
  const unsigned char* A = qh + ((size_t)e0 * 2048 + mw + (lane & 15)) * 32 + ((lane >> 4) << 3);
  const unsigned char* B = qw2 + ((size_t)e0 * 512 + c0 + (lane & 15)) * 32 + ((lane >> 4) << 3);
  f32x4 acc[32];
#pragma unroll
  for (int e = 0; e < 32; e++) {
    long a = *(const long*)(A + (size_t)e * 2048 * 32);
    long b = *(const long*)(B + (size_t)e * 512 * 32);
    f32x4 z = {0.f, 0.f, 0.f, 0.f};
    acc[e] = __builtin_amdgcn_mfma_f32_16x16x32_fp8_fp8(a, b, z, 0, 0, 0);
  }
  float* lw = lbuf + w * (64 * 34);
#pragma unroll
  for (int r = 0; r < 4; r++) {
#pragma unroll
    for (int g = 0; g < 8; g++) {
      *(float2*)&lw[lane * 34 + 4 * g] =
          make_float2(acc[4 * g + 0][r] * s2, acc[4 * g + 1][r] * s2);
      *(float2*)&lw[lane * 34 + 4 * g + 2] =
          make_float2(acc[4 * g + 2][r] * s2, acc[4 * g + 3][r] * s2);
    }
#pragma unroll
    for (int i = 0; i < 8; i++) {
      int p = i * 8 + (lane >> 3);
      float2 u0 = *(const float2*)&lw[p * 34 + (lane & 7) * 4];
      float2 u1 = *(const float2*)&lw[p * 34 + (lane & 7) * 4 + 2];
      float* dst = out + ((size_t)(mw + ((p >> 4) << 2) + r) * 512 + c0 + (p & 15)) * 128 +
                   e0 + (lane & 7) * 4;
      f32x4 vv = {u0.x, u0.y, u1.x, u1.y};
      __builtin_nontemporal_store(vv, (f32x4*)dst);
    }
  }
}

extern "C" void kernel_launch(void* const* d_in, const int* in_sizes, int n_in,
                              void* d_out, int out_size, void* d_ws, size_t ws_size,
                              hipStream_t stream) {
  const float* x  = (const float*)d_in[0];   // [2048][512]
  const float* w1 = (const float*)d_in[1];   // [512][4096]
  const float* w2 = (const float*)d_in[2];   // [512][4096]
  float* out = (float*)d_out;                // [2048][512][128]

  float* part  = (float*)d_ws;                         // 192 partial maxima (x,w1,w2)
  float* hpart = (float*)d_ws + 256;                   // 512 h partial maxima
  float* sc    = (float*)d_ws + 896;                   // [0]=s1 [1]=sw2 [2]=s2
  unsigned char* base = (unsigned char*)d_ws + 4096;
  unsigned char* qx   = base;                          // 1 MB  [2048][512]
  unsigned char* qw1t = qx   + (size_t)2048 * 512;     // 2 MB  [4096][512]
  unsigned char* qw2  = qw1t + (size_t)4096 * 512;     // 2 MB  [128][512][32]
  unsigned char* qh   = qw2  + (size_t)128 * 512 * 32; // 8 MB  [128][2048][32]
  float* h = (float*)(qh + (size_t)128 * 2048 * 32);   // 32 MB [2048][4096]

  k_amax3<<<dim3(64, 3), dim3(256), 0, stream>>>(x, w1, w2, part);
  k_quant_all<<<dim3(1280), dim3(256), 0, stream>>>(x, w1, w2, qx, qw1t, qw2, part, sc);
  k_gemm1<<<dim3(32, 16), dim3(256), 0, stream>>>(qx, qw1t, h, sc, hpart);
  k_quant_h<<<dim3(2048), dim3(256), 0, stream>>>(h, qh, hpart, sc);
  k_gemm2<<<dim3(2048), dim3(512), 0, stream>>>(qh, qw2, sc, out);
}